// Round 1
// baseline (222.353 us; speedup 1.0000x reference)
//
#include <hip/hip_runtime.h>

// out[b,d,n] = w[d] * in[b,d,n]; B=8, D=2048, N=2048, fp32.
// Pure streaming scale: 268 MB R+W, roofline ~43 us at 6.29 TB/s measured
// float4-copy ceiling (m13).
//
// Shape: 4096 blocks x 256 threads; each block owns 4 consecutive N-rows
// (4 x 512 float4 = 2048 float4, 32 KB contiguous). Each thread handles
// 8 float4s (k=0..7 at stride 256); row-in-block = k>>1 is compile-time
// uniform, so the scale pick is branch-free.
//   - 8 nontemporal dwordx4 loads issued back-to-back (128 B/lane MLP),
//     then 8 stores: deeper memory-level parallelism per wave than the
//     previous 2-load/2-store shape, fewer read<->write turnarounds.
//   - Rows [4b, 4b+4) are 4-aligned, so (4b)&2047 is a multiple of 4 and
//     the 4 weights are one 16B-aligned block-uniform load -> s_load_dwordx4.
//   - 32 data VGPRs keeps us in the <=64-VGPR bin: 8 waves/SIMD occupancy.
// Nontemporal ld/st: streaming data (268 MB >> 32 MB L2), no reuse.

typedef float floatx4 __attribute__((ext_vector_type(4)));

__global__ __launch_bounds__(256) void channel_scale_kernel(
    const floatx4* __restrict__ in, const float* __restrict__ w,
    floatx4* __restrict__ out) {
    const int b = blockIdx.x;            // owns rows [4b, 4b+4)
    const long base = (long)b * 2048;    // 4 rows * 512 float4/row
    const int t = threadIdx.x;

    // d of first row in this block; multiple of 4 -> 16B-aligned w load.
    const int d0 = (4 * b) & 2047;
    const floatx4 ws = *reinterpret_cast<const floatx4*>(w + d0);

    floatx4 v[8];
#pragma unroll
    for (int k = 0; k < 8; ++k)
        v[k] = __builtin_nontemporal_load(&in[base + t + k * 256]);

    // row-in-block = k>>1 (each row is 512 float4 = 2 strides of 256)
    v[0] *= ws.x; v[1] *= ws.x;
    v[2] *= ws.y; v[3] *= ws.y;
    v[4] *= ws.z; v[5] *= ws.z;
    v[6] *= ws.w; v[7] *= ws.w;

#pragma unroll
    for (int k = 0; k < 8; ++k)
        __builtin_nontemporal_store(v[k], &out[base + t + k * 256]);
}

extern "C" void kernel_launch(void* const* d_in, const int* in_sizes, int n_in,
                              void* d_out, int out_size, void* d_ws, size_t ws_size,
                              hipStream_t stream) {
    const floatx4* in = (const floatx4*)d_in[0];
    const float*   w  = (const float*)d_in[1];
    floatx4* out = (floatx4*)d_out;
    int rows = out_size / 2048;          // B*D = 16384 rows
    int blocks = rows / 4;               // 4096 blocks, 4 rows each
    channel_scale_kernel<<<blocks, 256, 0, stream>>>(in, w, out);
}